// Round 4
// baseline (442.096 us; speedup 1.0000x reference)
//
#include <hip/hip_runtime.h>

#define BUF_MASK 4194303u
#define BUF_SIZE 4194304
#define NFEAT 500000
#define FDIM 8
#define NLVL 4
#define NBINS 262144          // 64^3 Morton bins of size 0.8 (= level-3 cells)
#define NXCD 8

typedef float f4 __attribute__((ext_vector_type(4)));

// ---------- dtype detect: int64 vs int32 hash table --------------------------
__global__ void detect_int64_kernel(const unsigned int* __restrict__ fi,
                                    int* __restrict__ flag) {
    if (blockIdx.x == 0 && threadIdx.x == 0) {
        int cnt = 0;
        for (int k = 0; k < 128; ++k) {
            unsigned int w = fi[2 * k + 1];
            cnt += (w == 0u || w == 0xFFFFFFFFu) ? 1 : 0;
        }
        *flag = (cnt >= 96) ? 1 : 0;
    }
}

// ---------- Morton helpers ---------------------------------------------------
__device__ __forceinline__ unsigned part3(unsigned x) {
    x &= 0x3FFu;
    x = (x | (x << 16)) & 0x030000FFu;
    x = (x | (x << 8))  & 0x0300F00Fu;
    x = (x | (x << 4))  & 0x030C30C3u;
    x = (x | (x << 2))  & 0x09249249u;
    return x;
}

// ---------- pass 1: bin id + intra-bin rank ---------------------------------
__global__ __launch_bounds__(256) void bin_kernel(
    const float* __restrict__ qp, unsigned* __restrict__ hist,
    unsigned* __restrict__ binA, unsigned* __restrict__ rankA, int N)
{
    int i = blockIdx.x * blockDim.x + threadIdx.x;
    if (i >= N) return;
    float x = qp[3 * (size_t)i + 0];
    float y = qp[3 * (size_t)i + 1];
    float z = qp[3 * (size_t)i + 2];
    int cx = (int)floorf(x * 1.25f) + 32;  // 1/0.8
    int cy = (int)floorf(y * 1.25f) + 32;
    int cz = (int)floorf(z * 1.25f) + 32;
    cx = min(max(cx, 0), 63); cy = min(max(cy, 0), 63); cz = min(max(cz, 0), 63);
    unsigned m = (part3((unsigned)cx) << 2) | (part3((unsigned)cy) << 1) | part3((unsigned)cz);
    unsigned r = atomicAdd(&hist[m], 1u);
    binA[i] = m; rankA[i] = r;
}

// ---------- 3-kernel exclusive scan over NBINS = 512*512 --------------------
__global__ __launch_bounds__(512) void scan_block(
    const unsigned* __restrict__ hist, unsigned* __restrict__ starts,
    unsigned* __restrict__ bsum)
{
    __shared__ unsigned tmp[512];
    int b = blockIdx.x, t = threadIdx.x;
    unsigned v = hist[(size_t)b * 512 + t];
    tmp[t] = v; __syncthreads();
    for (int o = 1; o < 512; o <<= 1) {
        unsigned add = (t >= o) ? tmp[t - o] : 0u;
        __syncthreads();
        tmp[t] += add;
        __syncthreads();
    }
    starts[(size_t)b * 512 + t] = tmp[t] - v;      // exclusive within block
    if (t == 511) bsum[b] = tmp[t];
}

__global__ __launch_bounds__(512) void scan_sums(unsigned* __restrict__ bsum) {
    __shared__ unsigned tmp[512];
    int t = threadIdx.x;
    unsigned v = bsum[t];
    tmp[t] = v; __syncthreads();
    for (int o = 1; o < 512; o <<= 1) {
        unsigned add = (t >= o) ? tmp[t - o] : 0u;
        __syncthreads();
        tmp[t] += add;
        __syncthreads();
    }
    bsum[t] = tmp[t] - v;                          // exclusive block offsets
}

__global__ __launch_bounds__(512) void scan_add(
    unsigned* __restrict__ starts, const unsigned* __restrict__ bsum)
{
    starts[(size_t)blockIdx.x * 512 + threadIdx.x] += bsum[blockIdx.x];
}

// ---------- pass 2: scatter queries into Morton order -----------------------
__global__ __launch_bounds__(256) void scatter_kernel(
    const float* __restrict__ qp, const unsigned* __restrict__ binA,
    const unsigned* __restrict__ rankA, const unsigned* __restrict__ starts,
    float4* __restrict__ sorted, int N)
{
    int i = blockIdx.x * blockDim.x + threadIdx.x;
    if (i >= N) return;
    unsigned pos = starts[binA[i]] + rankA[i];
    sorted[pos] = make_float4(qp[3 * (size_t)i + 0], qp[3 * (size_t)i + 1],
                              qp[3 * (size_t)i + 2], __uint_as_float((unsigned)i));
}

// ---------- main: sorted, XCD-swizzled, BRANCHLESS speculative gathers ------
__global__ __launch_bounds__(256) void nvh_sorted_kernel(
    const f4* __restrict__ sq,        // (N) sorted {x,y,z,orig}
    const float* __restrict__ feats,  // (4, 500000, 8) f32
    const int*   __restrict__ fidx,   // (4, 4194304) int32/int64
    const int*   __restrict__ flagp,  // 0 => int32, 1 => int64
    float* __restrict__ out,          // [8N sums | N mask]
    int N)
{
    // bijective XCD swizzle: each XCD gets a contiguous chunk of sorted space
    unsigned nwg = gridDim.x, b = blockIdx.x;
    unsigned q = nwg / NXCD, r = nwg % NXCD;
    unsigned xcd = b % NXCD, off = b / NXCD;
    unsigned swz = (xcd < r ? xcd * (q + 1) : r * (q + 1) + (xcd - r) * q) + off;
    int i = (int)(swz * blockDim.x + threadIdx.x);
    if (i >= N) return;
    const int shift = *flagp;

    f4 qv = sq[i];
    float qx = qv.x, qy = qv.y, qz = qv.z;
    unsigned orig = __float_as_uint(qv.w);

    float frx[NLVL], fry[NLVL], frz[NLVL];
    int   idxs[NLVL][8];

    // Phase 1: all 32 hash-table gathers, full ILP, no branches.
    #pragma unroll
    for (int l = 0; l < NLVL; ++l) {
        const float vs = 0.1f * (float)(1 << l);
        float tx = qx / vs, ty = qy / vs, tz = qz / vs;
        float gx = floorf(tx), gy = floorf(ty), gz = floorf(tz);
        frx[l] = tx - gx; fry[l] = ty - gy; frz[l] = tz - gz;
        unsigned h = (unsigned)(int)gx * 73856093u
                   + (unsigned)(int)gy * 19349669u
                   + (unsigned)(int)gz * 83492791u;
        const int* base = fidx + (((size_t)l * BUF_SIZE) << shift);
        #pragma unroll
        for (int c = 0; c < 8; ++c) {
            unsigned key = h;
            if (c & 4) key += 73856093u;
            if (c & 2) key += 19349669u;
            if (c & 1) key += 83492791u;
            key &= BUF_MASK;
            idxs[l][c] = base[(size_t)key << shift];
        }
    }

    // Phase 2: branchless — validity folded into weights (valid?1:0 exact),
    // feature gathers depend only on their own idx (max MLP, no divergence).
    float acc[8] = {0.f, 0.f, 0.f, 0.f, 0.f, 0.f, 0.f, 0.f};
    float maskv = 0.0f;

    #pragma unroll
    for (int l = 0; l < NLVL; ++l) {
        int mn = idxs[l][0];
        #pragma unroll
        for (int c = 1; c < 8; ++c) mn = min(mn, idxs[l][c]);
        float m = (mn >= 0) ? 1.0f : 0.0f;
        if (l == 0) maskv = m;
        const float* fb = feats + (size_t)l * (size_t)NFEAT * FDIM;
        float tx = frx[l], ty = fry[l], tz = frz[l];
        float sx[2] = {1.0f - tx, tx};
        float sy[2] = {1.0f - ty, ty};
        float sz[2] = {1.0f - tz, tz};
        #pragma unroll
        for (int c = 0; c < 8; ++c) {
            float w = m * ((sx[(c >> 2) & 1] * sy[(c >> 1) & 1]) * sz[c & 1]);
            const f4* f4p = (const f4*)(fb + (size_t)max(idxs[l][c], 0) * FDIM);
            f4 a = f4p[0];
            f4 b2 = f4p[1];
            acc[0] += w * a.x;  acc[1] += w * a.y;
            acc[2] += w * a.z;  acc[3] += w * a.w;
            acc[4] += w * b2.x; acc[5] += w * b2.y;
            acc[6] += w * b2.z; acc[7] += w * b2.w;
        }
    }

    f4 o0 = {acc[0], acc[1], acc[2], acc[3]};
    f4 o1 = {acc[4], acc[5], acc[6], acc[7]};
    f4* op = (f4*)(out + (size_t)orig * 8);
    op[0] = o0;
    op[1] = o1;
    out[(size_t)8 * N + orig] = maskv;
}

// ---------- fallback if ws too small ----------------------------------------
__global__ __launch_bounds__(256) void nvh_kernel(
    const float* __restrict__ qp, const float* __restrict__ feats,
    const int* __restrict__ fidx, const int* __restrict__ flagp,
    float* __restrict__ out, int N)
{
    int i = blockIdx.x * blockDim.x + threadIdx.x;
    if (i >= N) return;
    const int shift = *flagp;
    float qx = qp[3 * (size_t)i + 0];
    float qy = qp[3 * (size_t)i + 1];
    float qz = qp[3 * (size_t)i + 2];
    float frx[NLVL], fry[NLVL], frz[NLVL];
    int   idxs[NLVL][8];
    #pragma unroll
    for (int l = 0; l < NLVL; ++l) {
        const float vs = 0.1f * (float)(1 << l);
        float tx = qx / vs, ty = qy / vs, tz = qz / vs;
        float gx = floorf(tx), gy = floorf(ty), gz = floorf(tz);
        frx[l] = tx - gx; fry[l] = ty - gy; frz[l] = tz - gz;
        unsigned h = (unsigned)(int)gx * 73856093u
                   + (unsigned)(int)gy * 19349669u
                   + (unsigned)(int)gz * 83492791u;
        const int* base = fidx + (((size_t)l * BUF_SIZE) << shift);
        #pragma unroll
        for (int c = 0; c < 8; ++c) {
            unsigned key = h;
            if (c & 4) key += 73856093u;
            if (c & 2) key += 19349669u;
            if (c & 1) key += 83492791u;
            key &= BUF_MASK;
            idxs[l][c] = base[(size_t)key << shift];
        }
    }
    float acc[8] = {0.f, 0.f, 0.f, 0.f, 0.f, 0.f, 0.f, 0.f};
    float maskv = 0.0f;
    #pragma unroll
    for (int l = 0; l < NLVL; ++l) {
        int mn = idxs[l][0];
        #pragma unroll
        for (int c = 1; c < 8; ++c) mn = min(mn, idxs[l][c]);
        float m = (mn >= 0) ? 1.0f : 0.0f;
        if (l == 0) maskv = m;
        const float* fb = feats + (size_t)l * (size_t)NFEAT * FDIM;
        float tx = frx[l], ty = fry[l], tz = frz[l];
        float sx[2] = {1.0f - tx, tx};
        float sy[2] = {1.0f - ty, ty};
        float sz[2] = {1.0f - tz, tz};
        #pragma unroll
        for (int c = 0; c < 8; ++c) {
            float w = m * ((sx[(c >> 2) & 1] * sy[(c >> 1) & 1]) * sz[c & 1]);
            const f4* f4p = (const f4*)(fb + (size_t)max(idxs[l][c], 0) * FDIM);
            f4 a = f4p[0];
            f4 b2 = f4p[1];
            acc[0] += w * a.x;  acc[1] += w * a.y;
            acc[2] += w * a.z;  acc[3] += w * a.w;
            acc[4] += w * b2.x; acc[5] += w * b2.y;
            acc[6] += w * b2.z; acc[7] += w * b2.w;
        }
    }
    float4* o = (float4*)(out + (size_t)i * 8);
    o[0] = make_float4(acc[0], acc[1], acc[2], acc[3]);
    o[1] = make_float4(acc[4], acc[5], acc[6], acc[7]);
    out[(size_t)8 * N + i] = maskv;
}

extern "C" void kernel_launch(void* const* d_in, const int* in_sizes, int n_in,
                              void* d_out, int out_size, void* d_ws, size_t ws_size,
                              hipStream_t stream) {
    const float* qp    = (const float*)d_in[0];
    const float* feats = (const float*)d_in[1];
    const int*   fidx  = (const int*)d_in[2];
    int N = in_sizes[0] / 3;
    int blocks = (N + 255) / 256;

    // ws layout
    char* ws = (char*)d_ws;
    size_t off = 0;
    int*      flag   = (int*)(ws + off);      off += 256;
    unsigned* hist   = (unsigned*)(ws + off); off += (size_t)NBINS * 4;
    unsigned* starts = (unsigned*)(ws + off); off += (size_t)NBINS * 4;
    unsigned* bsum   = (unsigned*)(ws + off); off += 512 * 4;
    unsigned* binA   = (unsigned*)(ws + off); off += (size_t)N * 4;
    unsigned* rankA  = (unsigned*)(ws + off); off += (size_t)N * 4;
    off = (off + 15) & ~(size_t)15;
    float4*   sorted = (float4*)(ws + off);   off += (size_t)N * 16;

    detect_int64_kernel<<<1, 64, 0, stream>>>((const unsigned int*)d_in[2], flag);

    if (ws_size < off) {
        nvh_kernel<<<blocks, 256, 0, stream>>>(qp, feats, fidx, flag, (float*)d_out, N);
        return;
    }

    hipMemsetAsync(hist, 0, (size_t)NBINS * 4, stream);
    bin_kernel<<<blocks, 256, 0, stream>>>(qp, hist, binA, rankA, N);
    scan_block<<<512, 512, 0, stream>>>(hist, starts, bsum);
    scan_sums<<<1, 512, 0, stream>>>(bsum);
    scan_add<<<512, 512, 0, stream>>>(starts, bsum);
    scatter_kernel<<<blocks, 256, 0, stream>>>(qp, binA, rankA, starts, sorted, N);
    nvh_sorted_kernel<<<blocks, 256, 0, stream>>>((const f4*)sorted, feats, fidx, flag, (float*)d_out, N);
}

// Round 5
// 415.184 us; speedup vs baseline: 1.0648x; 1.0648x over previous
//
#include <hip/hip_runtime.h>

#define BUF_MASK 4194303u
#define BUF_SIZE 4194304
#define NFEAT 500000
#define FDIM 8
#define NLVL 4
#define NBINS 262144          // 64^3 Morton bins of size 0.8 (= level-3 cells)
#define NXCD 8

typedef float f4 __attribute__((ext_vector_type(4)));
typedef _Float16 h8 __attribute__((ext_vector_type(8)));

// ---------- dtype detect: int64 vs int32 hash table --------------------------
__global__ void detect_int64_kernel(const unsigned int* __restrict__ fi,
                                    int* __restrict__ flag) {
    if (blockIdx.x == 0 && threadIdx.x == 0) {
        int cnt = 0;
        for (int k = 0; k < 128; ++k) {
            unsigned int w = fi[2 * k + 1];
            cnt += (w == 0u || w == 0xFFFFFFFFu) ? 1 : 0;
        }
        *flag = (cnt >= 96) ? 1 : 0;
    }
}

// ---------- table compression: idx -> int32, feats -> fp16 ------------------
__global__ __launch_bounds__(256) void conv_idx_kernel(
    const int* __restrict__ src, int* __restrict__ dst,
    const int* __restrict__ flagp, int ntot)
{
    int i = (blockIdx.x * blockDim.x + threadIdx.x) * 2;
    if (i >= ntot) return;
    if (*flagp) {
        const long long* s = (const long long*)src;
        dst[i]     = (int)s[i];
        dst[i + 1] = (int)s[i + 1];
    } else {
        dst[i]     = src[i];
        dst[i + 1] = src[i + 1];
    }
}

__global__ __launch_bounds__(256) void conv_feat_kernel(
    const float* __restrict__ src, _Float16* __restrict__ dst, int ntot)
{
    int i = (blockIdx.x * blockDim.x + threadIdx.x) * 8;
    if (i + 8 > ntot) return;
    f4 a = *(const f4*)(src + i);
    f4 b = *(const f4*)(src + i + 4);
    h8 o;
    o[0] = (_Float16)a.x; o[1] = (_Float16)a.y;
    o[2] = (_Float16)a.z; o[3] = (_Float16)a.w;
    o[4] = (_Float16)b.x; o[5] = (_Float16)b.y;
    o[6] = (_Float16)b.z; o[7] = (_Float16)b.w;
    *(h8*)(dst + i) = o;
}

// ---------- Morton helpers ---------------------------------------------------
__device__ __forceinline__ unsigned part3(unsigned x) {
    x &= 0x3FFu;
    x = (x | (x << 16)) & 0x030000FFu;
    x = (x | (x << 8))  & 0x0300F00Fu;
    x = (x | (x << 4))  & 0x030C30C3u;
    x = (x | (x << 2))  & 0x09249249u;
    return x;
}

// ---------- pass 1: bin id + intra-bin rank ---------------------------------
__global__ __launch_bounds__(256) void bin_kernel(
    const float* __restrict__ qp, unsigned* __restrict__ hist,
    unsigned* __restrict__ binA, unsigned* __restrict__ rankA, int N)
{
    int i = blockIdx.x * blockDim.x + threadIdx.x;
    if (i >= N) return;
    float x = qp[3 * (size_t)i + 0];
    float y = qp[3 * (size_t)i + 1];
    float z = qp[3 * (size_t)i + 2];
    int cx = (int)floorf(x * 1.25f) + 32;  // 1/0.8
    int cy = (int)floorf(y * 1.25f) + 32;
    int cz = (int)floorf(z * 1.25f) + 32;
    cx = min(max(cx, 0), 63); cy = min(max(cy, 0), 63); cz = min(max(cz, 0), 63);
    unsigned m = (part3((unsigned)cx) << 2) | (part3((unsigned)cy) << 1) | part3((unsigned)cz);
    unsigned r = atomicAdd(&hist[m], 1u);
    binA[i] = m; rankA[i] = r;
}

// ---------- 3-kernel exclusive scan over NBINS = 512*512 --------------------
__global__ __launch_bounds__(512) void scan_block(
    const unsigned* __restrict__ hist, unsigned* __restrict__ starts,
    unsigned* __restrict__ bsum)
{
    __shared__ unsigned tmp[512];
    int b = blockIdx.x, t = threadIdx.x;
    unsigned v = hist[(size_t)b * 512 + t];
    tmp[t] = v; __syncthreads();
    for (int o = 1; o < 512; o <<= 1) {
        unsigned add = (t >= o) ? tmp[t - o] : 0u;
        __syncthreads();
        tmp[t] += add;
        __syncthreads();
    }
    starts[(size_t)b * 512 + t] = tmp[t] - v;      // exclusive within block
    if (t == 511) bsum[b] = tmp[t];
}

__global__ __launch_bounds__(512) void scan_sums(unsigned* __restrict__ bsum) {
    __shared__ unsigned tmp[512];
    int t = threadIdx.x;
    unsigned v = bsum[t];
    tmp[t] = v; __syncthreads();
    for (int o = 1; o < 512; o <<= 1) {
        unsigned add = (t >= o) ? tmp[t - o] : 0u;
        __syncthreads();
        tmp[t] += add;
        __syncthreads();
    }
    bsum[t] = tmp[t] - v;                          // exclusive block offsets
}

__global__ __launch_bounds__(512) void scan_add(
    unsigned* __restrict__ starts, const unsigned* __restrict__ bsum)
{
    starts[(size_t)blockIdx.x * 512 + threadIdx.x] += bsum[blockIdx.x];
}

// ---------- pass 2: scatter queries into Morton order -----------------------
__global__ __launch_bounds__(256) void scatter_kernel(
    const float* __restrict__ qp, const unsigned* __restrict__ binA,
    const unsigned* __restrict__ rankA, const unsigned* __restrict__ starts,
    float4* __restrict__ sorted, int N)
{
    int i = blockIdx.x * blockDim.x + threadIdx.x;
    if (i >= N) return;
    unsigned pos = starts[binA[i]] + rankA[i];
    sorted[pos] = make_float4(qp[3 * (size_t)i + 0], qp[3 * (size_t)i + 1],
                              qp[3 * (size_t)i + 2], __uint_as_float((unsigned)i));
}

// ---------- main (compressed tables): int32 idx + fp16 feats ----------------
__global__ __launch_bounds__(256) void nvh_sorted_c(
    const f4* __restrict__ sq,            // (N) sorted {x,y,z,orig}
    const _Float16* __restrict__ feats,   // (4, 500000, 8) fp16
    const int* __restrict__ fidx,         // (4, 4194304) int32
    float* __restrict__ out, int N)
{
    unsigned nwg = gridDim.x, b = blockIdx.x;
    unsigned q = nwg / NXCD, r = nwg % NXCD;
    unsigned xcd = b % NXCD, off = b / NXCD;
    unsigned swz = (xcd < r ? xcd * (q + 1) : r * (q + 1) + (xcd - r) * q) + off;
    int i = (int)(swz * blockDim.x + threadIdx.x);
    if (i >= N) return;

    f4 qv = sq[i];
    float qx = qv.x, qy = qv.y, qz = qv.z;
    unsigned orig = __float_as_uint(qv.w);

    float frx[NLVL], fry[NLVL], frz[NLVL];
    int   idxs[NLVL][8];

    #pragma unroll
    for (int l = 0; l < NLVL; ++l) {
        const float vs = 0.1f * (float)(1 << l);
        float tx = qx / vs, ty = qy / vs, tz = qz / vs;
        float gx = floorf(tx), gy = floorf(ty), gz = floorf(tz);
        frx[l] = tx - gx; fry[l] = ty - gy; frz[l] = tz - gz;
        unsigned h = (unsigned)(int)gx * 73856093u
                   + (unsigned)(int)gy * 19349669u
                   + (unsigned)(int)gz * 83492791u;
        const int* base = fidx + (size_t)l * BUF_SIZE;
        #pragma unroll
        for (int c = 0; c < 8; ++c) {
            unsigned key = h;
            if (c & 4) key += 73856093u;
            if (c & 2) key += 19349669u;
            if (c & 1) key += 83492791u;
            idxs[l][c] = base[key & BUF_MASK];
        }
    }

    float acc[8] = {0.f, 0.f, 0.f, 0.f, 0.f, 0.f, 0.f, 0.f};
    float maskv = 0.0f;

    #pragma unroll
    for (int l = 0; l < NLVL; ++l) {
        int mn = idxs[l][0];
        #pragma unroll
        for (int c = 1; c < 8; ++c) mn = min(mn, idxs[l][c]);
        bool valid = (mn >= 0);
        if (l == 0) maskv = valid ? 1.0f : 0.0f;
        if (valid) {
            const _Float16* fb = feats + (size_t)l * (size_t)NFEAT * FDIM;
            float tx = frx[l], ty = fry[l], tz = frz[l];
            float sx[2] = {1.0f - tx, tx};
            float sy[2] = {1.0f - ty, ty};
            float sz[2] = {1.0f - tz, tz};
            #pragma unroll
            for (int c = 0; c < 8; ++c) {
                float w = (sx[(c >> 2) & 1] * sy[(c >> 1) & 1]) * sz[c & 1];
                h8 v = *(const h8*)(fb + (size_t)idxs[l][c] * FDIM);
                acc[0] += w * (float)v[0]; acc[1] += w * (float)v[1];
                acc[2] += w * (float)v[2]; acc[3] += w * (float)v[3];
                acc[4] += w * (float)v[4]; acc[5] += w * (float)v[5];
                acc[6] += w * (float)v[6]; acc[7] += w * (float)v[7];
            }
        }
    }

    f4 o0 = {acc[0], acc[1], acc[2], acc[3]};
    f4 o1 = {acc[4], acc[5], acc[6], acc[7]};
    f4* op = (f4*)(out + (size_t)orig * 8);
    op[0] = o0;
    op[1] = o1;
    out[(size_t)8 * N + orig] = maskv;
}

// ---------- main (original tables) — round-2 proven path --------------------
__global__ __launch_bounds__(256) void nvh_sorted_o(
    const f4* __restrict__ sq, const float* __restrict__ feats,
    const int* __restrict__ fidx, const int* __restrict__ flagp,
    float* __restrict__ out, int N)
{
    unsigned nwg = gridDim.x, b = blockIdx.x;
    unsigned q = nwg / NXCD, r = nwg % NXCD;
    unsigned xcd = b % NXCD, off = b / NXCD;
    unsigned swz = (xcd < r ? xcd * (q + 1) : r * (q + 1) + (xcd - r) * q) + off;
    int i = (int)(swz * blockDim.x + threadIdx.x);
    if (i >= N) return;
    const int shift = *flagp;

    f4 qv = sq[i];
    float qx = qv.x, qy = qv.y, qz = qv.z;
    unsigned orig = __float_as_uint(qv.w);

    float frx[NLVL], fry[NLVL], frz[NLVL];
    int   idxs[NLVL][8];

    #pragma unroll
    for (int l = 0; l < NLVL; ++l) {
        const float vs = 0.1f * (float)(1 << l);
        float tx = qx / vs, ty = qy / vs, tz = qz / vs;
        float gx = floorf(tx), gy = floorf(ty), gz = floorf(tz);
        frx[l] = tx - gx; fry[l] = ty - gy; frz[l] = tz - gz;
        unsigned h = (unsigned)(int)gx * 73856093u
                   + (unsigned)(int)gy * 19349669u
                   + (unsigned)(int)gz * 83492791u;
        const int* base = fidx + (((size_t)l * BUF_SIZE) << shift);
        #pragma unroll
        for (int c = 0; c < 8; ++c) {
            unsigned key = h;
            if (c & 4) key += 73856093u;
            if (c & 2) key += 19349669u;
            if (c & 1) key += 83492791u;
            key &= BUF_MASK;
            idxs[l][c] = base[(size_t)key << shift];
        }
    }

    float acc[8] = {0.f, 0.f, 0.f, 0.f, 0.f, 0.f, 0.f, 0.f};
    float maskv = 0.0f;

    #pragma unroll
    for (int l = 0; l < NLVL; ++l) {
        int mn = idxs[l][0];
        #pragma unroll
        for (int c = 1; c < 8; ++c) mn = min(mn, idxs[l][c]);
        bool valid = (mn >= 0);
        if (l == 0) maskv = valid ? 1.0f : 0.0f;
        if (valid) {
            const float* fb = feats + (size_t)l * (size_t)NFEAT * FDIM;
            float tx = frx[l], ty = fry[l], tz = frz[l];
            float sx[2] = {1.0f - tx, tx};
            float sy[2] = {1.0f - ty, ty};
            float sz[2] = {1.0f - tz, tz};
            #pragma unroll
            for (int c = 0; c < 8; ++c) {
                float w = (sx[(c >> 2) & 1] * sy[(c >> 1) & 1]) * sz[c & 1];
                const f4* f4p = (const f4*)(fb + (size_t)idxs[l][c] * FDIM);
                f4 a = f4p[0];
                f4 b2 = f4p[1];
                acc[0] += w * a.x;  acc[1] += w * a.y;
                acc[2] += w * a.z;  acc[3] += w * a.w;
                acc[4] += w * b2.x; acc[5] += w * b2.y;
                acc[6] += w * b2.z; acc[7] += w * b2.w;
            }
        }
    }

    f4 o0 = {acc[0], acc[1], acc[2], acc[3]};
    f4 o1 = {acc[4], acc[5], acc[6], acc[7]};
    f4* op = (f4*)(out + (size_t)orig * 8);
    op[0] = o0;
    op[1] = o1;
    out[(size_t)8 * N + orig] = maskv;
}

// ---------- fallback if ws too small ----------------------------------------
__global__ __launch_bounds__(256) void nvh_kernel(
    const float* __restrict__ qp, const float* __restrict__ feats,
    const int* __restrict__ fidx, const int* __restrict__ flagp,
    float* __restrict__ out, int N)
{
    int i = blockIdx.x * blockDim.x + threadIdx.x;
    if (i >= N) return;
    const int shift = *flagp;
    float qx = qp[3 * (size_t)i + 0];
    float qy = qp[3 * (size_t)i + 1];
    float qz = qp[3 * (size_t)i + 2];
    float frx[NLVL], fry[NLVL], frz[NLVL];
    int   idxs[NLVL][8];
    #pragma unroll
    for (int l = 0; l < NLVL; ++l) {
        const float vs = 0.1f * (float)(1 << l);
        float tx = qx / vs, ty = qy / vs, tz = qz / vs;
        float gx = floorf(tx), gy = floorf(ty), gz = floorf(tz);
        frx[l] = tx - gx; fry[l] = ty - gy; frz[l] = tz - gz;
        unsigned h = (unsigned)(int)gx * 73856093u
                   + (unsigned)(int)gy * 19349669u
                   + (unsigned)(int)gz * 83492791u;
        const int* base = fidx + (((size_t)l * BUF_SIZE) << shift);
        #pragma unroll
        for (int c = 0; c < 8; ++c) {
            unsigned key = h;
            if (c & 4) key += 73856093u;
            if (c & 2) key += 19349669u;
            if (c & 1) key += 83492791u;
            key &= BUF_MASK;
            idxs[l][c] = base[(size_t)key << shift];
        }
    }
    float acc[8] = {0.f, 0.f, 0.f, 0.f, 0.f, 0.f, 0.f, 0.f};
    float maskv = 0.0f;
    #pragma unroll
    for (int l = 0; l < NLVL; ++l) {
        int mn = idxs[l][0];
        #pragma unroll
        for (int c = 1; c < 8; ++c) mn = min(mn, idxs[l][c]);
        bool valid = (mn >= 0);
        if (l == 0) maskv = valid ? 1.0f : 0.0f;
        if (valid) {
            const float* fb = feats + (size_t)l * (size_t)NFEAT * FDIM;
            float tx = frx[l], ty = fry[l], tz = frz[l];
            float sx[2] = {1.0f - tx, tx};
            float sy[2] = {1.0f - ty, ty};
            float sz[2] = {1.0f - tz, tz};
            #pragma unroll
            for (int c = 0; c < 8; ++c) {
                float w = (sx[(c >> 2) & 1] * sy[(c >> 1) & 1]) * sz[c & 1];
                const f4* f4p = (const f4*)(fb + (size_t)idxs[l][c] * FDIM);
                f4 a = f4p[0];
                f4 b2 = f4p[1];
                acc[0] += w * a.x;  acc[1] += w * a.y;
                acc[2] += w * a.z;  acc[3] += w * a.w;
                acc[4] += w * b2.x; acc[5] += w * b2.y;
                acc[6] += w * b2.z; acc[7] += w * b2.w;
            }
        }
    }
    float4* o = (float4*)(out + (size_t)i * 8);
    o[0] = make_float4(acc[0], acc[1], acc[2], acc[3]);
    o[1] = make_float4(acc[4], acc[5], acc[6], acc[7]);
    out[(size_t)8 * N + i] = maskv;
}

extern "C" void kernel_launch(void* const* d_in, const int* in_sizes, int n_in,
                              void* d_out, int out_size, void* d_ws, size_t ws_size,
                              hipStream_t stream) {
    const float* qp    = (const float*)d_in[0];
    const float* feats = (const float*)d_in[1];
    const int*   fidx  = (const int*)d_in[2];
    int N = in_sizes[0] / 3;
    int blocks = (N + 255) / 256;

    const int IDX_TOT  = NLVL * BUF_SIZE;       // 16,777,216 entries
    const int FEAT_TOT = NLVL * NFEAT * FDIM;   // 16,000,000 floats

    // ws layout
    char* ws = (char*)d_ws;
    size_t off = 0;
    int*      flag   = (int*)(ws + off);      off += 256;
    unsigned* hist   = (unsigned*)(ws + off); off += (size_t)NBINS * 4;
    unsigned* starts = (unsigned*)(ws + off); off += (size_t)NBINS * 4;
    unsigned* bsum   = (unsigned*)(ws + off); off += 512 * 4;
    unsigned* binA   = (unsigned*)(ws + off); off += (size_t)N * 4;
    unsigned* rankA  = (unsigned*)(ws + off); off += (size_t)N * 4;
    off = (off + 15) & ~(size_t)15;
    float4*   sorted = (float4*)(ws + off);   off += (size_t)N * 16;
    size_t need_sort = off;
    off = (off + 15) & ~(size_t)15;
    int*      idx32  = (int*)(ws + off);      off += (size_t)IDX_TOT * 4;
    _Float16* feat16 = (_Float16*)(ws + off); off += (size_t)FEAT_TOT * 2;
    size_t need_full = off;

    detect_int64_kernel<<<1, 64, 0, stream>>>((const unsigned int*)d_in[2], flag);

    if (ws_size < need_sort) {
        nvh_kernel<<<blocks, 256, 0, stream>>>(qp, feats, fidx, flag, (float*)d_out, N);
        return;
    }

    bool full = (ws_size >= need_full);
    if (full) {
        conv_idx_kernel<<<IDX_TOT / 2 / 256, 256, 0, stream>>>(fidx, idx32, flag, IDX_TOT);
        conv_feat_kernel<<<(FEAT_TOT / 8 + 255) / 256, 256, 0, stream>>>(feats, feat16, FEAT_TOT);
    }

    hipMemsetAsync(hist, 0, (size_t)NBINS * 4, stream);
    bin_kernel<<<blocks, 256, 0, stream>>>(qp, hist, binA, rankA, N);
    scan_block<<<512, 512, 0, stream>>>(hist, starts, bsum);
    scan_sums<<<1, 512, 0, stream>>>(bsum);
    scan_add<<<512, 512, 0, stream>>>(starts, bsum);
    scatter_kernel<<<blocks, 256, 0, stream>>>(qp, binA, rankA, starts, sorted, N);

    if (full) {
        nvh_sorted_c<<<blocks, 256, 0, stream>>>((const f4*)sorted, feat16, idx32, (float*)d_out, N);
    } else {
        nvh_sorted_o<<<blocks, 256, 0, stream>>>((const f4*)sorted, feats, fidx, flag, (float*)d_out, N);
    }
}

// Round 6
// 402.585 us; speedup vs baseline: 1.0981x; 1.0313x over previous
//
#include <hip/hip_runtime.h>
#include <limits.h>

#define BUF_MASK 4194303u
#define BUF_SIZE 4194304
#define NFEAT 500000
#define FDIM 8
#define NLVL 4
#define NBINS 262144          // 64^3 Morton bins of size 0.8 (= level-3 cells)
#define NXCD 8
#define CAP 2048              // LDS lattice cache entries (idx 8KB + feat fp16 32KB)

typedef float f4 __attribute__((ext_vector_type(4)));
typedef _Float16 h8 __attribute__((ext_vector_type(8)));

// ---------- dtype detect: int64 vs int32 hash table --------------------------
__global__ void detect_int64_kernel(const unsigned int* __restrict__ fi,
                                    int* __restrict__ flag) {
    if (blockIdx.x == 0 && threadIdx.x == 0) {
        int cnt = 0;
        for (int k = 0; k < 128; ++k) {
            unsigned int w = fi[2 * k + 1];
            cnt += (w == 0u || w == 0xFFFFFFFFu) ? 1 : 0;
        }
        *flag = (cnt >= 96) ? 1 : 0;
    }
}

// ---------- Morton helpers ---------------------------------------------------
__device__ __forceinline__ unsigned part3(unsigned x) {
    x &= 0x3FFu;
    x = (x | (x << 16)) & 0x030000FFu;
    x = (x | (x << 8))  & 0x0300F00Fu;
    x = (x | (x << 4))  & 0x030C30C3u;
    x = (x | (x << 2))  & 0x09249249u;
    return x;
}

// ---------- pass 1: bin id + intra-bin rank ---------------------------------
__global__ __launch_bounds__(256) void bin_kernel(
    const float* __restrict__ qp, unsigned* __restrict__ hist,
    unsigned* __restrict__ binA, unsigned* __restrict__ rankA, int N)
{
    int i = blockIdx.x * blockDim.x + threadIdx.x;
    if (i >= N) return;
    float x = qp[3 * (size_t)i + 0];
    float y = qp[3 * (size_t)i + 1];
    float z = qp[3 * (size_t)i + 2];
    int cx = (int)floorf(x * 1.25f) + 32;  // 1/0.8
    int cy = (int)floorf(y * 1.25f) + 32;
    int cz = (int)floorf(z * 1.25f) + 32;
    cx = min(max(cx, 0), 63); cy = min(max(cy, 0), 63); cz = min(max(cz, 0), 63);
    unsigned m = (part3((unsigned)cx) << 2) | (part3((unsigned)cy) << 1) | part3((unsigned)cz);
    unsigned r = atomicAdd(&hist[m], 1u);
    binA[i] = m; rankA[i] = r;
}

// ---------- 3-kernel exclusive scan over NBINS = 512*512 --------------------
__global__ __launch_bounds__(512) void scan_block(
    const unsigned* __restrict__ hist, unsigned* __restrict__ starts,
    unsigned* __restrict__ bsum)
{
    __shared__ unsigned tmp[512];
    int b = blockIdx.x, t = threadIdx.x;
    unsigned v = hist[(size_t)b * 512 + t];
    tmp[t] = v; __syncthreads();
    for (int o = 1; o < 512; o <<= 1) {
        unsigned add = (t >= o) ? tmp[t - o] : 0u;
        __syncthreads();
        tmp[t] += add;
        __syncthreads();
    }
    starts[(size_t)b * 512 + t] = tmp[t] - v;      // exclusive within block
    if (t == 511) bsum[b] = tmp[t];
}

__global__ __launch_bounds__(512) void scan_sums(unsigned* __restrict__ bsum) {
    __shared__ unsigned tmp[512];
    int t = threadIdx.x;
    unsigned v = bsum[t];
    tmp[t] = v; __syncthreads();
    for (int o = 1; o < 512; o <<= 1) {
        unsigned add = (t >= o) ? tmp[t - o] : 0u;
        __syncthreads();
        tmp[t] += add;
        __syncthreads();
    }
    bsum[t] = tmp[t] - v;                          // exclusive block offsets
}

__global__ __launch_bounds__(512) void scan_add(
    unsigned* __restrict__ starts, const unsigned* __restrict__ bsum)
{
    starts[(size_t)blockIdx.x * 512 + threadIdx.x] += bsum[blockIdx.x];
}

// ---------- pass 2: scatter queries into Morton order -----------------------
__global__ __launch_bounds__(256) void scatter_kernel(
    const float* __restrict__ qp, const unsigned* __restrict__ binA,
    const unsigned* __restrict__ rankA, const unsigned* __restrict__ starts,
    float4* __restrict__ sorted, int N)
{
    int i = blockIdx.x * blockDim.x + threadIdx.x;
    if (i >= N) return;
    unsigned pos = starts[binA[i]] + rankA[i];
    sorted[pos] = make_float4(qp[3 * (size_t)i + 0], qp[3 * (size_t)i + 1],
                              qp[3 * (size_t)i + 2], __uint_as_float((unsigned)i));
}

// ---------- main: sorted + XCD swizzle + per-level block-lattice dedup ------
__global__ __launch_bounds__(512) void nvh_dedup(
    const f4* __restrict__ sq,        // (N) sorted {x,y,z,orig}
    const float* __restrict__ feats,  // (4, 500000, 8) f32
    const int*   __restrict__ fidx,   // (4, 4194304) int32/int64
    const int*   __restrict__ flagp,  // 0 => int32, 1 => int64
    float* __restrict__ out,          // [8N sums | N mask]
    int N)
{
    __shared__ int s_idx[CAP];        // 8 KB
    __shared__ h8  s_feat[CAP];       // 32 KB
    __shared__ int s_red[8][6];       // per-wave {mnx,mny,mnz,mxx,mxy,mxz}

    // bijective XCD swizzle
    unsigned nwg = gridDim.x, b = blockIdx.x;
    unsigned q = nwg / NXCD, r = nwg % NXCD;
    unsigned xcd = b % NXCD, offb = b / NXCD;
    unsigned swz = (xcd < r ? xcd * (q + 1) : r * (q + 1) + (xcd - r) * q) + offb;
    int i = (int)(swz * blockDim.x + threadIdx.x);
    bool active = (i < N);
    const int shift = *flagp;
    int tid = threadIdx.x, wid = tid >> 6;

    f4 qv = {0.f, 0.f, 0.f, 0.f};
    if (active) qv = sq[i];
    float qx = qv.x, qy = qv.y, qz = qv.z;
    unsigned orig = __float_as_uint(qv.w);

    float acc[8] = {0.f, 0.f, 0.f, 0.f, 0.f, 0.f, 0.f, 0.f};
    float maskv = 0.0f;

    for (int l = 0; l < NLVL; ++l) {
        const float vs = 0.1f * (float)(1 << l);
        float tx = qx / vs, ty = qy / vs, tz = qz / vs;
        float gxf = floorf(tx), gyf = floorf(ty), gzf = floorf(tz);
        float fx = tx - gxf, fy = ty - gyf, fz = tz - gzf;
        int gx = (int)gxf, gy = (int)gyf, gz = (int)gzf;

        // ---- block AABB of grid coords (active threads only) ----
        int a0 = active ? gx : INT_MAX, a1 = active ? gy : INT_MAX, a2 = active ? gz : INT_MAX;
        int b0 = active ? gx : INT_MIN, b1 = active ? gy : INT_MIN, b2 = active ? gz : INT_MIN;
        #pragma unroll
        for (int o = 32; o; o >>= 1) {
            a0 = min(a0, __shfl_xor(a0, o)); b0 = max(b0, __shfl_xor(b0, o));
            a1 = min(a1, __shfl_xor(a1, o)); b1 = max(b1, __shfl_xor(b1, o));
            a2 = min(a2, __shfl_xor(a2, o)); b2 = max(b2, __shfl_xor(b2, o));
        }
        __syncthreads();   // SYNC_A: prior-level LDS reads done; s_red reusable
        if ((tid & 63) == 0) {
            s_red[wid][0] = a0; s_red[wid][1] = a1; s_red[wid][2] = a2;
            s_red[wid][3] = b0; s_red[wid][4] = b1; s_red[wid][5] = b2;
        }
        __syncthreads();   // SYNC_B
        int mnx = s_red[0][0], mny = s_red[0][1], mnz = s_red[0][2];
        int mxx = s_red[0][3], mxy = s_red[0][4], mxz = s_red[0][5];
        #pragma unroll
        for (int w = 1; w < 8; ++w) {
            mnx = min(mnx, s_red[w][0]); mny = min(mny, s_red[w][1]); mnz = min(mnz, s_red[w][2]);
            mxx = max(mxx, s_red[w][3]); mxy = max(mxy, s_red[w][4]); mxz = max(mxz, s_red[w][5]);
        }

        int dx = mxx - mnx + 2, dy = mxy - mny + 2, dz = mxz - mnz + 2;
        long long T = (long long)dx * dy * dz;
        const int* base = fidx + (((size_t)l * BUF_SIZE) << shift);
        const float* fb = feats + (size_t)l * (size_t)NFEAT * FDIM;

        if (T <= (long long)CAP) {
            // ---- dedup path: fetch each lattice corner once ----
            int Ti = (int)T;
            for (int t = tid; t < Ti; t += 512) {
                int ox = t % dx, rem = t / dx;
                int oy = rem % dy, oz = rem / dy;
                unsigned h = (unsigned)(mnx + ox) * 73856093u
                           + (unsigned)(mny + oy) * 19349669u
                           + (unsigned)(mnz + oz) * 83492791u;
                int id = base[(size_t)(h & BUF_MASK) << shift];
                s_idx[t] = id;
                if (id >= 0) {
                    const f4* fp = (const f4*)(fb + (size_t)id * FDIM);
                    f4 va = fp[0], vb = fp[1];
                    h8 hv;
                    hv[0] = (_Float16)va.x; hv[1] = (_Float16)va.y;
                    hv[2] = (_Float16)va.z; hv[3] = (_Float16)va.w;
                    hv[4] = (_Float16)vb.x; hv[5] = (_Float16)vb.y;
                    hv[6] = (_Float16)vb.z; hv[7] = (_Float16)vb.w;
                    s_feat[t] = hv;
                }
            }
            __syncthreads();   // SYNC_C
            if (active) {
                int bx = gx - mnx, by = gy - mny, bz = gz - mnz;
                int offs[8], idxs[8];
                #pragma unroll
                for (int c = 0; c < 8; ++c) {
                    int off = (bx + ((c >> 2) & 1))
                            + dx * ((by + ((c >> 1) & 1)) + dy * (bz + (c & 1)));
                    offs[c] = off;
                    idxs[c] = s_idx[off];
                }
                int mn = idxs[0];
                #pragma unroll
                for (int c = 1; c < 8; ++c) mn = min(mn, idxs[c]);
                bool valid = (mn >= 0);
                if (l == 0) maskv = valid ? 1.0f : 0.0f;
                if (valid) {
                    float sx[2] = {1.0f - fx, fx};
                    float sy[2] = {1.0f - fy, fy};
                    float sz[2] = {1.0f - fz, fz};
                    #pragma unroll
                    for (int c = 0; c < 8; ++c) {
                        float w = (sx[(c >> 2) & 1] * sy[(c >> 1) & 1]) * sz[c & 1];
                        h8 v = s_feat[offs[c]];
                        acc[0] += w * (float)v[0]; acc[1] += w * (float)v[1];
                        acc[2] += w * (float)v[2]; acc[3] += w * (float)v[3];
                        acc[4] += w * (float)v[4]; acc[5] += w * (float)v[5];
                        acc[6] += w * (float)v[6]; acc[7] += w * (float)v[7];
                    }
                }
            }
        } else {
            // ---- direct path (exact round-2 semantics, f32 feats) ----
            if (active) {
                unsigned h = (unsigned)gx * 73856093u
                           + (unsigned)gy * 19349669u
                           + (unsigned)gz * 83492791u;
                int idxs[8];
                #pragma unroll
                for (int c = 0; c < 8; ++c) {
                    unsigned key = h;
                    if (c & 4) key += 73856093u;
                    if (c & 2) key += 19349669u;
                    if (c & 1) key += 83492791u;
                    key &= BUF_MASK;
                    idxs[c] = base[(size_t)key << shift];
                }
                int mn = idxs[0];
                #pragma unroll
                for (int c = 1; c < 8; ++c) mn = min(mn, idxs[c]);
                bool valid = (mn >= 0);
                if (l == 0) maskv = valid ? 1.0f : 0.0f;
                if (valid) {
                    float sx[2] = {1.0f - fx, fx};
                    float sy[2] = {1.0f - fy, fy};
                    float sz[2] = {1.0f - fz, fz};
                    #pragma unroll
                    for (int c = 0; c < 8; ++c) {
                        float w = (sx[(c >> 2) & 1] * sy[(c >> 1) & 1]) * sz[c & 1];
                        const f4* f4p = (const f4*)(fb + (size_t)idxs[c] * FDIM);
                        f4 va = f4p[0], vb = f4p[1];
                        acc[0] += w * va.x; acc[1] += w * va.y;
                        acc[2] += w * va.z; acc[3] += w * va.w;
                        acc[4] += w * vb.x; acc[5] += w * vb.y;
                        acc[6] += w * vb.z; acc[7] += w * vb.w;
                    }
                }
            }
        }
    }

    if (active) {
        f4 o0 = {acc[0], acc[1], acc[2], acc[3]};
        f4 o1 = {acc[4], acc[5], acc[6], acc[7]};
        f4* op = (f4*)(out + (size_t)orig * 8);
        op[0] = o0;
        op[1] = o1;
        out[(size_t)8 * N + orig] = maskv;
    }
}

// ---------- fallback if ws too small ----------------------------------------
__global__ __launch_bounds__(256) void nvh_kernel(
    const float* __restrict__ qp, const float* __restrict__ feats,
    const int* __restrict__ fidx, const int* __restrict__ flagp,
    float* __restrict__ out, int N)
{
    int i = blockIdx.x * blockDim.x + threadIdx.x;
    if (i >= N) return;
    const int shift = *flagp;
    float qx = qp[3 * (size_t)i + 0];
    float qy = qp[3 * (size_t)i + 1];
    float qz = qp[3 * (size_t)i + 2];
    float frx[NLVL], fry[NLVL], frz[NLVL];
    int   idxs[NLVL][8];
    #pragma unroll
    for (int l = 0; l < NLVL; ++l) {
        const float vs = 0.1f * (float)(1 << l);
        float tx = qx / vs, ty = qy / vs, tz = qz / vs;
        float gx = floorf(tx), gy = floorf(ty), gz = floorf(tz);
        frx[l] = tx - gx; fry[l] = ty - gy; frz[l] = tz - gz;
        unsigned h = (unsigned)(int)gx * 73856093u
                   + (unsigned)(int)gy * 19349669u
                   + (unsigned)(int)gz * 83492791u;
        const int* base = fidx + (((size_t)l * BUF_SIZE) << shift);
        #pragma unroll
        for (int c = 0; c < 8; ++c) {
            unsigned key = h;
            if (c & 4) key += 73856093u;
            if (c & 2) key += 19349669u;
            if (c & 1) key += 83492791u;
            key &= BUF_MASK;
            idxs[l][c] = base[(size_t)key << shift];
        }
    }
    float acc[8] = {0.f, 0.f, 0.f, 0.f, 0.f, 0.f, 0.f, 0.f};
    float maskv = 0.0f;
    #pragma unroll
    for (int l = 0; l < NLVL; ++l) {
        int mn = idxs[l][0];
        #pragma unroll
        for (int c = 1; c < 8; ++c) mn = min(mn, idxs[l][c]);
        bool valid = (mn >= 0);
        if (l == 0) maskv = valid ? 1.0f : 0.0f;
        if (valid) {
            const float* fb = feats + (size_t)l * (size_t)NFEAT * FDIM;
            float tx = frx[l], ty = fry[l], tz = frz[l];
            float sx[2] = {1.0f - tx, tx};
            float sy[2] = {1.0f - ty, ty};
            float sz[2] = {1.0f - tz, tz};
            #pragma unroll
            for (int c = 0; c < 8; ++c) {
                float w = (sx[(c >> 2) & 1] * sy[(c >> 1) & 1]) * sz[c & 1];
                const f4* f4p = (const f4*)(fb + (size_t)idxs[l][c] * FDIM);
                f4 a = f4p[0];
                f4 b2 = f4p[1];
                acc[0] += w * a.x;  acc[1] += w * a.y;
                acc[2] += w * a.z;  acc[3] += w * a.w;
                acc[4] += w * b2.x; acc[5] += w * b2.y;
                acc[6] += w * b2.z; acc[7] += w * b2.w;
            }
        }
    }
    float4* o = (float4*)(out + (size_t)i * 8);
    o[0] = make_float4(acc[0], acc[1], acc[2], acc[3]);
    o[1] = make_float4(acc[4], acc[5], acc[6], acc[7]);
    out[(size_t)8 * N + i] = maskv;
}

extern "C" void kernel_launch(void* const* d_in, const int* in_sizes, int n_in,
                              void* d_out, int out_size, void* d_ws, size_t ws_size,
                              hipStream_t stream) {
    const float* qp    = (const float*)d_in[0];
    const float* feats = (const float*)d_in[1];
    const int*   fidx  = (const int*)d_in[2];
    int N = in_sizes[0] / 3;
    int blocks = (N + 255) / 256;
    int blocks512 = (N + 511) / 512;

    // ws layout
    char* ws = (char*)d_ws;
    size_t off = 0;
    int*      flag   = (int*)(ws + off);      off += 256;
    unsigned* hist   = (unsigned*)(ws + off); off += (size_t)NBINS * 4;
    unsigned* starts = (unsigned*)(ws + off); off += (size_t)NBINS * 4;
    unsigned* bsum   = (unsigned*)(ws + off); off += 512 * 4;
    unsigned* binA   = (unsigned*)(ws + off); off += (size_t)N * 4;
    unsigned* rankA  = (unsigned*)(ws + off); off += (size_t)N * 4;
    off = (off + 15) & ~(size_t)15;
    float4*   sorted = (float4*)(ws + off);   off += (size_t)N * 16;
    size_t need_sort = off;

    detect_int64_kernel<<<1, 64, 0, stream>>>((const unsigned int*)d_in[2], flag);

    if (ws_size < need_sort) {
        nvh_kernel<<<blocks, 256, 0, stream>>>(qp, feats, fidx, flag, (float*)d_out, N);
        return;
    }

    hipMemsetAsync(hist, 0, (size_t)NBINS * 4, stream);
    bin_kernel<<<blocks, 256, 0, stream>>>(qp, hist, binA, rankA, N);
    scan_block<<<512, 512, 0, stream>>>(hist, starts, bsum);
    scan_sums<<<1, 512, 0, stream>>>(bsum);
    scan_add<<<512, 512, 0, stream>>>(starts, bsum);
    scatter_kernel<<<blocks, 256, 0, stream>>>(qp, binA, rankA, starts, sorted, N);
    nvh_dedup<<<blocks512, 512, 0, stream>>>((const f4*)sorted, feats, fidx, flag, (float*)d_out, N);
}

// Round 7
// 382.822 us; speedup vs baseline: 1.1548x; 1.0516x over previous
//
#include <hip/hip_runtime.h>

#define BUF_MASK 4194303u
#define BUF_SIZE 4194304
#define NFEAT 500000
#define FDIM 8
#define NLVL 4
#define NBINS 262144          // 64^3 Morton bins of size 0.8 (= level-3 cells)
#define NXCD 8

typedef float f4 __attribute__((ext_vector_type(4)));

// ---------- dtype detect: int64 vs int32 hash table --------------------------
__global__ void detect_int64_kernel(const unsigned int* __restrict__ fi,
                                    int* __restrict__ flag) {
    if (blockIdx.x == 0 && threadIdx.x == 0) {
        int cnt = 0;
        for (int k = 0; k < 128; ++k) {
            unsigned int w = fi[2 * k + 1];
            cnt += (w == 0u || w == 0xFFFFFFFFu) ? 1 : 0;
        }
        *flag = (cnt >= 96) ? 1 : 0;
    }
}

// ---------- Morton helpers ---------------------------------------------------
__device__ __forceinline__ unsigned part3(unsigned x) {
    x &= 0x3FFu;
    x = (x | (x << 16)) & 0x030000FFu;
    x = (x | (x << 8))  & 0x0300F00Fu;
    x = (x | (x << 4))  & 0x030C30C3u;
    x = (x | (x << 2))  & 0x09249249u;
    return x;
}

// ---------- pass 1: bin id + intra-bin rank ---------------------------------
__global__ __launch_bounds__(256) void bin_kernel(
    const float* __restrict__ qp, unsigned* __restrict__ hist,
    unsigned* __restrict__ binA, unsigned* __restrict__ rankA, int N)
{
    int i = blockIdx.x * blockDim.x + threadIdx.x;
    if (i >= N) return;
    float x = qp[3 * (size_t)i + 0];
    float y = qp[3 * (size_t)i + 1];
    float z = qp[3 * (size_t)i + 2];
    int cx = (int)floorf(x * 1.25f) + 32;  // 1/0.8
    int cy = (int)floorf(y * 1.25f) + 32;
    int cz = (int)floorf(z * 1.25f) + 32;
    cx = min(max(cx, 0), 63); cy = min(max(cy, 0), 63); cz = min(max(cz, 0), 63);
    unsigned m = (part3((unsigned)cx) << 2) | (part3((unsigned)cy) << 1) | part3((unsigned)cz);
    unsigned r = atomicAdd(&hist[m], 1u);
    binA[i] = m; rankA[i] = r;
}

// ---------- scan over NBINS = 512*512 (block offsets folded into scatter) ----
__global__ __launch_bounds__(512) void scan_block(
    const unsigned* __restrict__ hist, unsigned* __restrict__ starts,
    unsigned* __restrict__ bsum)
{
    __shared__ unsigned tmp[512];
    int b = blockIdx.x, t = threadIdx.x;
    unsigned v = hist[(size_t)b * 512 + t];
    tmp[t] = v; __syncthreads();
    for (int o = 1; o < 512; o <<= 1) {
        unsigned add = (t >= o) ? tmp[t - o] : 0u;
        __syncthreads();
        tmp[t] += add;
        __syncthreads();
    }
    starts[(size_t)b * 512 + t] = tmp[t] - v;      // exclusive within block
    if (t == 511) bsum[b] = tmp[t];
}

__global__ __launch_bounds__(512) void scan_sums(unsigned* __restrict__ bsum) {
    __shared__ unsigned tmp[512];
    int t = threadIdx.x;
    unsigned v = bsum[t];
    tmp[t] = v; __syncthreads();
    for (int o = 1; o < 512; o <<= 1) {
        unsigned add = (t >= o) ? tmp[t - o] : 0u;
        __syncthreads();
        tmp[t] += add;
        __syncthreads();
    }
    bsum[t] = tmp[t] - v;                          // exclusive block offsets
}

// ---------- pass 2: scatter queries into Morton order -----------------------
__global__ __launch_bounds__(256) void scatter_kernel(
    const float* __restrict__ qp, const unsigned* __restrict__ binA,
    const unsigned* __restrict__ rankA, const unsigned* __restrict__ starts,
    const unsigned* __restrict__ bsum, float4* __restrict__ sorted, int N)
{
    int i = blockIdx.x * blockDim.x + threadIdx.x;
    if (i >= N) return;
    unsigned bin = binA[i];
    unsigned pos = starts[bin] + bsum[bin >> 9] + rankA[i];
    sorted[pos] = make_float4(qp[3 * (size_t)i + 0], qp[3 * (size_t)i + 1],
                              qp[3 * (size_t)i + 2], __uint_as_float((unsigned)i));
}

// ---------- main: sorted, XCD-swizzled, straight-line dummy-row gathers -----
__global__ __launch_bounds__(256) void nvh_sorted_kernel(
    const f4* __restrict__ sq,        // (N) sorted {x,y,z,orig}
    const float* __restrict__ feats,  // (4, 500000, 8) f32
    const int*   __restrict__ fidx,   // (4, 4194304) int32/int64
    const int*   __restrict__ flagp,  // 0 => int32, 1 => int64
    float* __restrict__ out,          // [8N sums | N mask]
    int N)
{
    // bijective XCD swizzle: each XCD gets a contiguous chunk of sorted space
    unsigned nwg = gridDim.x, b = blockIdx.x;
    unsigned q = nwg / NXCD, r = nwg % NXCD;
    unsigned xcd = b % NXCD, off = b / NXCD;
    unsigned swz = (xcd < r ? xcd * (q + 1) : r * (q + 1) + (xcd - r) * q) + off;
    int i = (int)(swz * blockDim.x + threadIdx.x);
    if (i >= N) return;
    const int shift = *flagp;

    f4 qv = sq[i];
    float qx = qv.x, qy = qv.y, qz = qv.z;
    unsigned orig = __float_as_uint(qv.w);

    float frx[NLVL], fry[NLVL], frz[NLVL];
    int   idxs[NLVL][8];

    // Phase 1: all 32 hash-table gathers, full ILP, no branches.
    #pragma unroll
    for (int l = 0; l < NLVL; ++l) {
        const float vs = 0.1f * (float)(1 << l);
        float tx = qx / vs, ty = qy / vs, tz = qz / vs;
        float gx = floorf(tx), gy = floorf(ty), gz = floorf(tz);
        frx[l] = tx - gx; fry[l] = ty - gy; frz[l] = tz - gz;
        unsigned h = (unsigned)(int)gx * 73856093u
                   + (unsigned)(int)gy * 19349669u
                   + (unsigned)(int)gz * 83492791u;
        const int* base = fidx + (((size_t)l * BUF_SIZE) << shift);
        #pragma unroll
        for (int c = 0; c < 8; ++c) {
            unsigned key = h;
            if (c & 4) key += 73856093u;   // x step
            if (c & 2) key += 19349669u;   // y step
            if (c & 1) key += 83492791u;   // z step
            key &= BUF_MASK;
            idxs[l][c] = base[(size_t)key << shift];
        }
    }

    // Phase 2: straight-line, branch-free. Invalid levels gather row 0
    // (single L2-hot line, ~zero extra HBM traffic) with weight 0 (exact).
    float acc[8] = {0.f, 0.f, 0.f, 0.f, 0.f, 0.f, 0.f, 0.f};
    float maskv = 0.0f;

    #pragma unroll
    for (int l = 0; l < NLVL; ++l) {
        int mn = idxs[l][0];
        #pragma unroll
        for (int c = 1; c < 8; ++c) mn = min(mn, idxs[l][c]);
        bool valid = (mn >= 0);
        float m = valid ? 1.0f : 0.0f;
        if (l == 0) maskv = m;

        const float* fb = feats + (size_t)l * (size_t)NFEAT * FDIM;
        float tx = frx[l], ty = fry[l], tz = frz[l];
        float sx[2] = {1.0f - tx, tx};
        float sy[2] = {1.0f - ty, ty};
        float sz[2] = {1.0f - tz, tz};

        // load all 8 corners' rows first (issues 16 dwordx4 loads back-to-back)
        f4 va[8], vb[8];
        #pragma unroll
        for (int c = 0; c < 8; ++c) {
            int safe = valid ? idxs[l][c] : 0;
            const f4* fp = (const f4*)(fb + (size_t)safe * FDIM);
            va[c] = fp[0];
            vb[c] = fp[1];
        }
        #pragma unroll
        for (int c = 0; c < 8; ++c) {
            float w = m * ((sx[(c >> 2) & 1] * sy[(c >> 1) & 1]) * sz[c & 1]);
            acc[0] += w * va[c].x; acc[1] += w * va[c].y;
            acc[2] += w * va[c].z; acc[3] += w * va[c].w;
            acc[4] += w * vb[c].x; acc[5] += w * vb[c].y;
            acc[6] += w * vb[c].z; acc[7] += w * vb[c].w;
        }
    }

    f4 o0 = {acc[0], acc[1], acc[2], acc[3]};
    f4 o1 = {acc[4], acc[5], acc[6], acc[7]};
    f4* op = (f4*)(out + (size_t)orig * 8);
    op[0] = o0;
    op[1] = o1;
    out[(size_t)8 * N + orig] = maskv;
}

// ---------- fallback if ws too small ----------------------------------------
__global__ __launch_bounds__(256) void nvh_kernel(
    const float* __restrict__ qp, const float* __restrict__ feats,
    const int* __restrict__ fidx, const int* __restrict__ flagp,
    float* __restrict__ out, int N)
{
    int i = blockIdx.x * blockDim.x + threadIdx.x;
    if (i >= N) return;
    const int shift = *flagp;
    float qx = qp[3 * (size_t)i + 0];
    float qy = qp[3 * (size_t)i + 1];
    float qz = qp[3 * (size_t)i + 2];
    float frx[NLVL], fry[NLVL], frz[NLVL];
    int   idxs[NLVL][8];
    #pragma unroll
    for (int l = 0; l < NLVL; ++l) {
        const float vs = 0.1f * (float)(1 << l);
        float tx = qx / vs, ty = qy / vs, tz = qz / vs;
        float gx = floorf(tx), gy = floorf(ty), gz = floorf(tz);
        frx[l] = tx - gx; fry[l] = ty - gy; frz[l] = tz - gz;
        unsigned h = (unsigned)(int)gx * 73856093u
                   + (unsigned)(int)gy * 19349669u
                   + (unsigned)(int)gz * 83492791u;
        const int* base = fidx + (((size_t)l * BUF_SIZE) << shift);
        #pragma unroll
        for (int c = 0; c < 8; ++c) {
            unsigned key = h;
            if (c & 4) key += 73856093u;
            if (c & 2) key += 19349669u;
            if (c & 1) key += 83492791u;
            key &= BUF_MASK;
            idxs[l][c] = base[(size_t)key << shift];
        }
    }
    float acc[8] = {0.f, 0.f, 0.f, 0.f, 0.f, 0.f, 0.f, 0.f};
    float maskv = 0.0f;
    #pragma unroll
    for (int l = 0; l < NLVL; ++l) {
        int mn = idxs[l][0];
        #pragma unroll
        for (int c = 1; c < 8; ++c) mn = min(mn, idxs[l][c]);
        bool valid = (mn >= 0);
        if (l == 0) maskv = valid ? 1.0f : 0.0f;
        if (valid) {
            const float* fb = feats + (size_t)l * (size_t)NFEAT * FDIM;
            float tx = frx[l], ty = fry[l], tz = frz[l];
            float sx[2] = {1.0f - tx, tx};
            float sy[2] = {1.0f - ty, ty};
            float sz[2] = {1.0f - tz, tz};
            #pragma unroll
            for (int c = 0; c < 8; ++c) {
                float w = (sx[(c >> 2) & 1] * sy[(c >> 1) & 1]) * sz[c & 1];
                const f4* f4p = (const f4*)(fb + (size_t)idxs[l][c] * FDIM);
                f4 a = f4p[0];
                f4 b2 = f4p[1];
                acc[0] += w * a.x;  acc[1] += w * a.y;
                acc[2] += w * a.z;  acc[3] += w * a.w;
                acc[4] += w * b2.x; acc[5] += w * b2.y;
                acc[6] += w * b2.z; acc[7] += w * b2.w;
            }
        }
    }
    float4* o = (float4*)(out + (size_t)i * 8);
    o[0] = make_float4(acc[0], acc[1], acc[2], acc[3]);
    o[1] = make_float4(acc[4], acc[5], acc[6], acc[7]);
    out[(size_t)8 * N + i] = maskv;
}

extern "C" void kernel_launch(void* const* d_in, const int* in_sizes, int n_in,
                              void* d_out, int out_size, void* d_ws, size_t ws_size,
                              hipStream_t stream) {
    const float* qp    = (const float*)d_in[0];
    const float* feats = (const float*)d_in[1];
    const int*   fidx  = (const int*)d_in[2];
    int N = in_sizes[0] / 3;
    int blocks = (N + 255) / 256;

    // ws layout
    char* ws = (char*)d_ws;
    size_t off = 0;
    int*      flag   = (int*)(ws + off);      off += 256;
    unsigned* hist   = (unsigned*)(ws + off); off += (size_t)NBINS * 4;
    unsigned* starts = (unsigned*)(ws + off); off += (size_t)NBINS * 4;
    unsigned* bsum   = (unsigned*)(ws + off); off += 512 * 4;
    unsigned* binA   = (unsigned*)(ws + off); off += (size_t)N * 4;
    unsigned* rankA  = (unsigned*)(ws + off); off += (size_t)N * 4;
    off = (off + 15) & ~(size_t)15;
    float4*   sorted = (float4*)(ws + off);   off += (size_t)N * 16;
    size_t need_sort = off;

    detect_int64_kernel<<<1, 64, 0, stream>>>((const unsigned int*)d_in[2], flag);

    if (ws_size < need_sort) {
        nvh_kernel<<<blocks, 256, 0, stream>>>(qp, feats, fidx, flag, (float*)d_out, N);
        return;
    }

    hipMemsetAsync(hist, 0, (size_t)NBINS * 4, stream);
    bin_kernel<<<blocks, 256, 0, stream>>>(qp, hist, binA, rankA, N);
    scan_block<<<512, 512, 0, stream>>>(hist, starts, bsum);
    scan_sums<<<1, 512, 0, stream>>>(bsum);
    scatter_kernel<<<blocks, 256, 0, stream>>>(qp, binA, rankA, starts, bsum, sorted, N);
    nvh_sorted_kernel<<<blocks, 256, 0, stream>>>((const f4*)sorted, feats, fidx, flag, (float*)d_out, N);
}

// Round 8
// 372.044 us; speedup vs baseline: 1.1883x; 1.0290x over previous
//
#include <hip/hip_runtime.h>

#define BUF_MASK 4194303u
#define BUF_SIZE 4194304
#define NFEAT 500000
#define FDIM 8
#define NLVL 4
#define NBINS 262144          // 64^3 Morton bins of size 0.8 (= level-3 cells)
#define NXCD 8

typedef float f4 __attribute__((ext_vector_type(4)));

// ---------- dtype detect: int64 vs int32 hash table --------------------------
__global__ void detect_int64_kernel(const unsigned int* __restrict__ fi,
                                    int* __restrict__ flag) {
    if (blockIdx.x == 0 && threadIdx.x == 0) {
        int cnt = 0;
        for (int k = 0; k < 128; ++k) {
            unsigned int w = fi[2 * k + 1];
            cnt += (w == 0u || w == 0xFFFFFFFFu) ? 1 : 0;
        }
        *flag = (cnt >= 96) ? 1 : 0;
    }
}

// ---------- Morton helpers ---------------------------------------------------
__device__ __forceinline__ unsigned part3(unsigned x) {
    x &= 0x3FFu;
    x = (x | (x << 16)) & 0x030000FFu;
    x = (x | (x << 8))  & 0x0300F00Fu;
    x = (x | (x << 4))  & 0x030C30C3u;
    x = (x | (x << 2))  & 0x09249249u;
    return x;
}

// ---------- pass 1: bin id + intra-bin rank ---------------------------------
__global__ __launch_bounds__(256) void bin_kernel(
    const float* __restrict__ qp, unsigned* __restrict__ hist,
    unsigned* __restrict__ binA, unsigned* __restrict__ rankA, int N)
{
    int i = blockIdx.x * blockDim.x + threadIdx.x;
    if (i >= N) return;
    float x = qp[3 * (size_t)i + 0];
    float y = qp[3 * (size_t)i + 1];
    float z = qp[3 * (size_t)i + 2];
    int cx = (int)floorf(x * 1.25f) + 32;  // 1/0.8
    int cy = (int)floorf(y * 1.25f) + 32;
    int cz = (int)floorf(z * 1.25f) + 32;
    cx = min(max(cx, 0), 63); cy = min(max(cy, 0), 63); cz = min(max(cz, 0), 63);
    unsigned m = (part3((unsigned)cx) << 2) | (part3((unsigned)cy) << 1) | part3((unsigned)cz);
    unsigned r = atomicAdd(&hist[m], 1u);
    binA[i] = m; rankA[i] = r;
}

// ---------- scan over NBINS = 512*512 (block offsets folded into scatter) ----
__global__ __launch_bounds__(512) void scan_block(
    const unsigned* __restrict__ hist, unsigned* __restrict__ starts,
    unsigned* __restrict__ bsum)
{
    __shared__ unsigned tmp[512];
    int b = blockIdx.x, t = threadIdx.x;
    unsigned v = hist[(size_t)b * 512 + t];
    tmp[t] = v; __syncthreads();
    for (int o = 1; o < 512; o <<= 1) {
        unsigned add = (t >= o) ? tmp[t - o] : 0u;
        __syncthreads();
        tmp[t] += add;
        __syncthreads();
    }
    starts[(size_t)b * 512 + t] = tmp[t] - v;      // exclusive within block
    if (t == 511) bsum[b] = tmp[t];
}

__global__ __launch_bounds__(512) void scan_sums(unsigned* __restrict__ bsum) {
    __shared__ unsigned tmp[512];
    int t = threadIdx.x;
    unsigned v = bsum[t];
    tmp[t] = v; __syncthreads();
    for (int o = 1; o < 512; o <<= 1) {
        unsigned add = (t >= o) ? tmp[t - o] : 0u;
        __syncthreads();
        tmp[t] += add;
        __syncthreads();
    }
    bsum[t] = tmp[t] - v;                          // exclusive block offsets
}

// ---------- pass 2: scatter queries into Morton order -----------------------
__global__ __launch_bounds__(256) void scatter_kernel(
    const float* __restrict__ qp, const unsigned* __restrict__ binA,
    const unsigned* __restrict__ rankA, const unsigned* __restrict__ starts,
    const unsigned* __restrict__ bsum, float4* __restrict__ sorted, int N)
{
    int i = blockIdx.x * blockDim.x + threadIdx.x;
    if (i >= N) return;
    unsigned bin = binA[i];
    unsigned pos = starts[bin] + bsum[bin >> 9] + rankA[i];
    sorted[pos] = make_float4(qp[3 * (size_t)i + 0], qp[3 * (size_t)i + 1],
                              qp[3 * (size_t)i + 2], __uint_as_float((unsigned)i));
}

// ---------- main: sorted order, XCD-swizzled (exact round-2 form) -----------
__global__ __launch_bounds__(256) void nvh_sorted_kernel(
    const f4* __restrict__ sq,        // (N) sorted {x,y,z,orig}
    const float* __restrict__ feats,  // (4, 500000, 8) f32
    const int*   __restrict__ fidx,   // (4, 4194304) int32/int64
    const int*   __restrict__ flagp,  // 0 => int32, 1 => int64
    float* __restrict__ out,          // [8N sums | N mask]
    int N)
{
    // bijective XCD swizzle: each XCD gets a contiguous chunk of sorted space
    unsigned nwg = gridDim.x, b = blockIdx.x;
    unsigned q = nwg / NXCD, r = nwg % NXCD;
    unsigned xcd = b % NXCD, off = b / NXCD;
    unsigned swz = (xcd < r ? xcd * (q + 1) : r * (q + 1) + (xcd - r) * q) + off;
    int i = (int)(swz * blockDim.x + threadIdx.x);
    if (i >= N) return;
    const int shift = *flagp;

    f4 qv = sq[i];
    float qx = qv.x, qy = qv.y, qz = qv.z;
    unsigned orig = __float_as_uint(qv.w);

    float frx[NLVL], fry[NLVL], frz[NLVL];
    int   idxs[NLVL][8];

    // Phase 1: all 32 hash-table gathers, full ILP.
    #pragma unroll
    for (int l = 0; l < NLVL; ++l) {
        const float vs = 0.1f * (float)(1 << l);
        float tx = qx / vs, ty = qy / vs, tz = qz / vs;
        float gx = floorf(tx), gy = floorf(ty), gz = floorf(tz);
        frx[l] = tx - gx; fry[l] = ty - gy; frz[l] = tz - gz;
        unsigned h = (unsigned)(int)gx * 73856093u
                   + (unsigned)(int)gy * 19349669u
                   + (unsigned)(int)gz * 83492791u;
        const int* base = fidx + (((size_t)l * BUF_SIZE) << shift);
        #pragma unroll
        for (int c = 0; c < 8; ++c) {
            unsigned key = h;
            if (c & 4) key += 73856093u;   // x step
            if (c & 2) key += 19349669u;   // y step
            if (c & 1) key += 83492791u;   // z step
            key &= BUF_MASK;
            idxs[l][c] = base[(size_t)key << shift];
        }
    }

    // Phase 2: branchy per-level — skips feature gathers for invalid levels
    // (measured optimal: every added gather costs ~a line of fill traffic).
    float acc[8] = {0.f, 0.f, 0.f, 0.f, 0.f, 0.f, 0.f, 0.f};
    float maskv = 0.0f;

    #pragma unroll
    for (int l = 0; l < NLVL; ++l) {
        int mn = idxs[l][0];
        #pragma unroll
        for (int c = 1; c < 8; ++c) mn = min(mn, idxs[l][c]);
        bool valid = (mn >= 0);
        if (l == 0) maskv = valid ? 1.0f : 0.0f;
        if (valid) {
            const float* fb = feats + (size_t)l * (size_t)NFEAT * FDIM;
            float tx = frx[l], ty = fry[l], tz = frz[l];
            float sx[2] = {1.0f - tx, tx};
            float sy[2] = {1.0f - ty, ty};
            float sz[2] = {1.0f - tz, tz};
            #pragma unroll
            for (int c = 0; c < 8; ++c) {
                float w = (sx[(c >> 2) & 1] * sy[(c >> 1) & 1]) * sz[c & 1];
                const f4* f4p = (const f4*)(fb + (size_t)idxs[l][c] * FDIM);
                f4 a = f4p[0];
                f4 b2 = f4p[1];
                acc[0] += w * a.x;  acc[1] += w * a.y;
                acc[2] += w * a.z;  acc[3] += w * a.w;
                acc[4] += w * b2.x; acc[5] += w * b2.y;
                acc[6] += w * b2.z; acc[7] += w * b2.w;
            }
        }
    }

    f4 o0 = {acc[0], acc[1], acc[2], acc[3]};
    f4 o1 = {acc[4], acc[5], acc[6], acc[7]};
    f4* op = (f4*)(out + (size_t)orig * 8);
    op[0] = o0;
    op[1] = o1;
    out[(size_t)8 * N + orig] = maskv;
}

// ---------- fallback if ws too small ----------------------------------------
__global__ __launch_bounds__(256) void nvh_kernel(
    const float* __restrict__ qp, const float* __restrict__ feats,
    const int* __restrict__ fidx, const int* __restrict__ flagp,
    float* __restrict__ out, int N)
{
    int i = blockIdx.x * blockDim.x + threadIdx.x;
    if (i >= N) return;
    const int shift = *flagp;
    float qx = qp[3 * (size_t)i + 0];
    float qy = qp[3 * (size_t)i + 1];
    float qz = qp[3 * (size_t)i + 2];
    float frx[NLVL], fry[NLVL], frz[NLVL];
    int   idxs[NLVL][8];
    #pragma unroll
    for (int l = 0; l < NLVL; ++l) {
        const float vs = 0.1f * (float)(1 << l);
        float tx = qx / vs, ty = qy / vs, tz = qz / vs;
        float gx = floorf(tx), gy = floorf(ty), gz = floorf(tz);
        frx[l] = tx - gx; fry[l] = ty - gy; frz[l] = tz - gz;
        unsigned h = (unsigned)(int)gx * 73856093u
                   + (unsigned)(int)gy * 19349669u
                   + (unsigned)(int)gz * 83492791u;
        const int* base = fidx + (((size_t)l * BUF_SIZE) << shift);
        #pragma unroll
        for (int c = 0; c < 8; ++c) {
            unsigned key = h;
            if (c & 4) key += 73856093u;
            if (c & 2) key += 19349669u;
            if (c & 1) key += 83492791u;
            key &= BUF_MASK;
            idxs[l][c] = base[(size_t)key << shift];
        }
    }
    float acc[8] = {0.f, 0.f, 0.f, 0.f, 0.f, 0.f, 0.f, 0.f};
    float maskv = 0.0f;
    #pragma unroll
    for (int l = 0; l < NLVL; ++l) {
        int mn = idxs[l][0];
        #pragma unroll
        for (int c = 1; c < 8; ++c) mn = min(mn, idxs[l][c]);
        bool valid = (mn >= 0);
        if (l == 0) maskv = valid ? 1.0f : 0.0f;
        if (valid) {
            const float* fb = feats + (size_t)l * (size_t)NFEAT * FDIM;
            float tx = frx[l], ty = fry[l], tz = frz[l];
            float sx[2] = {1.0f - tx, tx};
            float sy[2] = {1.0f - ty, ty};
            float sz[2] = {1.0f - tz, tz};
            #pragma unroll
            for (int c = 0; c < 8; ++c) {
                float w = (sx[(c >> 2) & 1] * sy[(c >> 1) & 1]) * sz[c & 1];
                const f4* f4p = (const f4*)(fb + (size_t)idxs[l][c] * FDIM);
                f4 a = f4p[0];
                f4 b2 = f4p[1];
                acc[0] += w * a.x;  acc[1] += w * a.y;
                acc[2] += w * a.z;  acc[3] += w * a.w;
                acc[4] += w * b2.x; acc[5] += w * b2.y;
                acc[6] += w * b2.z; acc[7] += w * b2.w;
            }
        }
    }
    float4* o = (float4*)(out + (size_t)i * 8);
    o[0] = make_float4(acc[0], acc[1], acc[2], acc[3]);
    o[1] = make_float4(acc[4], acc[5], acc[6], acc[7]);
    out[(size_t)8 * N + i] = maskv;
}

extern "C" void kernel_launch(void* const* d_in, const int* in_sizes, int n_in,
                              void* d_out, int out_size, void* d_ws, size_t ws_size,
                              hipStream_t stream) {
    const float* qp    = (const float*)d_in[0];
    const float* feats = (const float*)d_in[1];
    const int*   fidx  = (const int*)d_in[2];
    int N = in_sizes[0] / 3;
    int blocks = (N + 255) / 256;

    // ws layout
    char* ws = (char*)d_ws;
    size_t off = 0;
    int*      flag   = (int*)(ws + off);      off += 256;
    unsigned* hist   = (unsigned*)(ws + off); off += (size_t)NBINS * 4;
    unsigned* starts = (unsigned*)(ws + off); off += (size_t)NBINS * 4;
    unsigned* bsum   = (unsigned*)(ws + off); off += 512 * 4;
    unsigned* binA   = (unsigned*)(ws + off); off += (size_t)N * 4;
    unsigned* rankA  = (unsigned*)(ws + off); off += (size_t)N * 4;
    off = (off + 15) & ~(size_t)15;
    float4*   sorted = (float4*)(ws + off);   off += (size_t)N * 16;
    size_t need_sort = off;

    detect_int64_kernel<<<1, 64, 0, stream>>>((const unsigned int*)d_in[2], flag);

    if (ws_size < need_sort) {
        nvh_kernel<<<blocks, 256, 0, stream>>>(qp, feats, fidx, flag, (float*)d_out, N);
        return;
    }

    hipMemsetAsync(hist, 0, (size_t)NBINS * 4, stream);
    bin_kernel<<<blocks, 256, 0, stream>>>(qp, hist, binA, rankA, N);
    scan_block<<<512, 512, 0, stream>>>(hist, starts, bsum);
    scan_sums<<<1, 512, 0, stream>>>(bsum);
    scatter_kernel<<<blocks, 256, 0, stream>>>(qp, binA, rankA, starts, bsum, sorted, N);
    nvh_sorted_kernel<<<blocks, 256, 0, stream>>>((const f4*)sorted, feats, fidx, flag, (float*)d_out, N);
}